// Round 1
// 1114.267 us; speedup vs baseline: 1.3908x; 1.3908x over previous
//
#include <hip/hip_runtime.h>

typedef unsigned short u16;
typedef unsigned int   u32;
typedef __attribute__((ext_vector_type(8))) short s8v;   // 8 bf16 (as shorts) = 4 VGPRs
typedef __attribute__((ext_vector_type(4))) float f4v;   // MFMA C/D frag

constexpr int B_ = 8, C_ = 256, F_ = 64, T_ = 500, H_ = 512;
constexpr int TT = 30;        // output t-columns per block
constexpr int S_ = 32;        // slots = TT + 2 (halo)
constexpr int NTILE = 17;     // ceil(500/30)

constexpr int HROW = 520;     // u16 / hb row (1040B: 16B-aligned, 4-bank skew)
constexpr int XROW = 264;     // u16 / xs row (528B: 16B-aligned)

// LDS map (52,256 B total -> 3 blocks/CU on 160KB):
//   hb  [34][520] u16 @ 0        (rows 2..33 alias as h2b[0..31]; rows 32,33 = GEMM2 N-pad, zeroed)
//   xs  [32][264] u16 @ 35360    (bf16 x tile; dead after P1)
//   wred[8][32][2] f32 @ 35360   (aliases xs; live from P6)
//   statm/statr 32 f32 @ +2048/+2176
constexpr int OFF_HB = 0;
constexpr int OFF_XS = 34 * HROW * 2;            // 35360
constexpr int OFF_WR = OFF_XS;
constexpr int OFF_SM = OFF_XS + 2048;
constexpr int OFF_SR = OFF_SM + 128;
constexpr int SMEM_BYTES = OFF_XS + 32 * XROW * 2;   // 52256

__device__ __forceinline__ u16 f2bf(float f) {
  unsigned u = __float_as_uint(f);
  u += 0x7FFFu + ((u >> 16) & 1u);        // RNE
  return (u16)(u >> 16);
}
__device__ __forceinline__ float bf2f(u16 h) {
  return __uint_as_float(((unsigned)h) << 16);
}

__global__ void prep_kernel(const float* __restrict__ pw, const float* __restrict__ qw,
                            u16* __restrict__ wa, u16* __restrict__ wb) {
  int i = blockIdx.x * blockDim.x + threadIdx.x;   // 131072 threads exactly
  wa[i] = f2bf(pw[i]);
  wb[i] = f2bf(qw[i]);
}

__global__ __launch_bounds__(512, 6)   // force VGPR<=~84 so 3 blocks/CU (24 waves) fit
void mixer_kernel(const float* __restrict__ x, const float* __restrict__ state,
                  const float* __restrict__ pre_b, const float* __restrict__ pre_nw,
                  const float* __restrict__ pre_nb,
                  const float* __restrict__ dw_w, const float* __restrict__ dw_b,
                  const float* __restrict__ dw_nw, const float* __restrict__ dw_nb,
                  const float* __restrict__ post_b, const float* __restrict__ post_nw,
                  const float* __restrict__ post_nb,
                  const u16* __restrict__ wpre, const u16* __restrict__ wpost,
                  float* __restrict__ out0, float* __restrict__ out1) {
  extern __shared__ char smem[];
  u16*   hb    = (u16*)  (smem + OFF_HB);   // [34][520]
  u16*   h2b   = hb + 2 * HROW;             // [32][520] = hb rows 2..33
  u16*   xs    = (u16*)  (smem + OFF_XS);   // [32][264] bf16 x tile
  float* wred  = (float*)(smem + OFF_WR);   // [8][32][2] per-wave col partials (aliases xs)
  float* statm = (float*)(smem + OFF_SM);
  float* statr = (float*)(smem + OFF_SR);

  const int tid  = threadIdx.x;
  const int bx   = blockIdx.x;
  const int tile = bx % NTILE;
  const int f    = (bx / NTILE) % F_;
  const int b    = bx / (NTILE * F_);
  const int t0   = tile * TT;

  const int w    = tid >> 6;        // wave 0..7
  const int lane = tid & 63;
  const int quad = lane >> 4;
  const int l16  = lane & 15;

  // ---- P0: stage x tile as bf16 pairs (slot s -> t = t0-2+s), zero OOB ----
  {
    const float* xp = x + ((size_t)b * C_ * F_ + f) * T_;
    for (int e = tid; e < 128 * S_; e += 512) {     // 4096 c-pairs
      int cpair = e >> 5, s = e & 31;
      int c = cpair * 2;
      int t = t0 - 2 + s;
      float va = 0.f, vb = 0.f;
      if (t >= 0 && t < T_) {
        va = xp[(size_t)c * F_ * T_ + t];
        vb = xp[(size_t)(c + 1) * F_ * T_ + t];
      }
      u32 pk = (u32)f2bf(va) | ((u32)f2bf(vb) << 16);
      *(u32*)(xs + s * XROW + c) = pk;
    }
    // zero hb rows 32,33 == h2b N-pad rows 30,31 (read by GEMM2, values unused)
    hb[32 * HROW + tid] = 0;
    hb[33 * HROW + tid] = 0;
  }
  __syncthreads();

  // ---- P1: GEMM1  D[s][o] = x^T * pre_w^T ;  relu(+pre_b) -> hb (bf16) ----
  {
    f4v acc[2][4];
#pragma unroll
    for (int mi = 0; mi < 2; mi++)
#pragma unroll
      for (int j = 0; j < 4; j++) acc[mi][j] = (f4v){0.f, 0.f, 0.f, 0.f};

    const u16* wp[4];
#pragma unroll
    for (int j = 0; j < 4; j++)
      wp[j] = wpre + ((w + 8 * j) * 16 + l16) * C_ + quad * 8;
    const u16* a0p = xs + l16 * XROW + quad * 8;
    const u16* a1p = xs + (16 + l16) * XROW + quad * 8;

#pragma unroll 2
    for (int k = 0; k < 8; k++) {
      int c0 = k * 32;
      s8v af0 = *(const s8v*)(a0p + c0);
      s8v af1 = *(const s8v*)(a1p + c0);
#pragma unroll
      for (int j = 0; j < 4; j++) {
        s8v bf = *(const s8v*)(wp[j] + c0);
        acc[0][j] = __builtin_amdgcn_mfma_f32_16x16x32_bf16(af0, bf, acc[0][j], 0, 0, 0);
        acc[1][j] = __builtin_amdgcn_mfma_f32_16x16x32_bf16(af1, bf, acc[1][j], 0, 0, 0);
      }
    }
#pragma unroll
    for (int j = 0; j < 4; j++) {
      int o = (w + 8 * j) * 16 + l16;
      float pb = pre_b[o];
#pragma unroll
      for (int mi = 0; mi < 2; mi++)
#pragma unroll
        for (int r2 = 0; r2 < 4; r2++) {
          int s = mi * 16 + quad * 4 + r2;      // D row = m
          float v = fmaxf(acc[mi][j][r2] + pb, 0.f);
          hb[s * HROW + o] = f2bf(v);
        }
    }
  }
  __syncthreads();

  // ---- P2: per-slot stats over 512 ch + normalize in place (16 thr / row, u16-pair ops) ----
  {
    int r = tid >> 4, p = tid & 15;
    u16* row = hb + r * HROW;
    float sum = 0.f, ss = 0.f;
#pragma unroll
    for (int i = 0; i < 16; i++) {
      u32 pk = *(const u32*)(row + 2 * p + (i << 5));
      float v0 = bf2f((u16)(pk & 0xffffu)), v1 = bf2f((u16)(pk >> 16));
      sum += v0 + v1; ss += v0 * v0 + v1 * v1;
    }
#pragma unroll
    for (int mm = 1; mm < 16; mm <<= 1) {
      sum += __shfl_xor(sum, mm, 16);
      ss  += __shfl_xor(ss,  mm, 16);
    }
    float mean = sum * (1.f / 512.f);
    float var  = ss * (1.f / 512.f) - mean * mean;
    float rs   = rsqrtf(var + 1e-8f);
#pragma unroll
    for (int i = 0; i < 16; i++) {
      int o = 2 * p + (i << 5);
      u32 pk = *(const u32*)(row + o);
      float2 nw2 = *(const float2*)(pre_nw + o);
      float2 nb2 = *(const float2*)(pre_nb + o);
      float v0 = (bf2f((u16)(pk & 0xffffu)) - mean) * rs * nw2.x + nb2.x;
      float v1 = (bf2f((u16)(pk >> 16))     - mean) * rs * nw2.y + nb2.y;
      *(u32*)(row + o) = (u32)f2bf(v0) | ((u32)f2bf(v1) << 16);
    }
  }
  __syncthreads();

  // ---- P3: edges. tile0: halo slots 0,1 <- raw state. last tile: emit new_state ----
  {
    int o = tid;   // 512 threads == H_
    if (tile == 0) {
      const float* sp = state + (((size_t)b * H_ + o) * F_ + f) * 2;
      hb[0 * HROW + o] = f2bf(sp[0]);
      hb[1 * HROW + o] = f2bf(sp[1]);
    }
    if (tile == NTILE - 1) {
      float* op = out1 + (((size_t)b * H_ + o) * F_ + f) * 2;
      op[0] = bf2f(hb[(T_ - t0) * HROW + o]);       // slot of t=498
      op[1] = bf2f(hb[(T_ - t0 + 1) * HROW + o]);   // slot of t=499
    }
  }
  __syncthreads();

  // ---- P4: depthwise K=3 along t + relu, IN PLACE (h2b = hb shifted 2 rows) ----
  {
    int o = tid;
    float w0 = dw_w[o * 3 + 0], w1 = dw_w[o * 3 + 1], w2 = dw_w[o * 3 + 2];
    float db = dw_b[o];
    float v0 = bf2f(hb[0 * HROW + o]);
    float v1 = bf2f(hb[1 * HROW + o]);
#pragma unroll 6
    for (int s = 2; s < 32; s++) {
      float v2 = bf2f(hb[s * HROW + o]);   // read before aliased write below
      int t = t0 + s - 2;
      float r = fmaxf(w0 * v0 + w1 * v1 + w2 * v2 + db, 0.f);
      h2b[(s - 2) * HROW + o] = (t < T_) ? f2bf(r) : (u16)0;   // == hb[s*HROW+o]
      v0 = v1; v1 = v2;
    }
  }
  __syncthreads();

  // ---- P5: stats+normalize h2b rows 0..29 (u16-pair ops) ----
  {
    int r = tid >> 4, p = tid & 15;
    if (r < TT) {
      u16* row = h2b + r * HROW;
      float sum = 0.f, ss = 0.f;
#pragma unroll
      for (int i = 0; i < 16; i++) {
        u32 pk = *(const u32*)(row + 2 * p + (i << 5));
        float v0 = bf2f((u16)(pk & 0xffffu)), v1 = bf2f((u16)(pk >> 16));
        sum += v0 + v1; ss += v0 * v0 + v1 * v1;
      }
#pragma unroll
      for (int mm = 1; mm < 16; mm <<= 1) {
        sum += __shfl_xor(sum, mm, 16);
        ss  += __shfl_xor(ss,  mm, 16);
      }
      float mean = sum * (1.f / 512.f);
      float var  = ss * (1.f / 512.f) - mean * mean;
      float rs   = rsqrtf(var + 1e-8f);
#pragma unroll
      for (int i = 0; i < 16; i++) {
        int o = 2 * p + (i << 5);
        u32 pk = *(const u32*)(row + o);
        float2 nw2 = *(const float2*)(dw_nw + o);
        float2 nb2 = *(const float2*)(dw_nb + o);
        float v0 = (bf2f((u16)(pk & 0xffffu)) - mean) * rs * nw2.x + nb2.x;
        float v1 = (bf2f((u16)(pk >> 16))     - mean) * rs * nw2.y + nb2.y;
        *(u32*)(row + o) = (u32)f2bf(v0) | ((u32)f2bf(v1) << 16);
      }
    }
  }
  __syncthreads();

  // ---- P6: GEMM2  D[c][s2] = post_w * h2 (acc stays in registers) ----
  f4v acc[2][2];
  float pb[2][4];
  {
#pragma unroll
    for (int mi = 0; mi < 2; mi++)
#pragma unroll
      for (int ni = 0; ni < 2; ni++) acc[mi][ni] = (f4v){0.f, 0.f, 0.f, 0.f};

    const u16* ap0 = wpost + ((2 * w + 0) * 16 + l16) * H_ + quad * 8;
    const u16* ap1 = wpost + ((2 * w + 1) * 16 + l16) * H_ + quad * 8;
    const u16* bp0 = h2b + (0 + l16) * HROW + quad * 8;
    const u16* bp1 = h2b + (16 + l16) * HROW + quad * 8;

#pragma unroll 4
    for (int k = 0; k < 16; k++) {
      int ko = k * 32;
      s8v a0 = *(const s8v*)(ap0 + ko);
      s8v a1 = *(const s8v*)(ap1 + ko);
      s8v b0 = *(const s8v*)(bp0 + ko);
      s8v b1 = *(const s8v*)(bp1 + ko);
      acc[0][0] = __builtin_amdgcn_mfma_f32_16x16x32_bf16(a0, b0, acc[0][0], 0, 0, 0);
      acc[0][1] = __builtin_amdgcn_mfma_f32_16x16x32_bf16(a0, b1, acc[0][1], 0, 0, 0);
      acc[1][0] = __builtin_amdgcn_mfma_f32_16x16x32_bf16(a1, b0, acc[1][0], 0, 0, 0);
      acc[1][1] = __builtin_amdgcn_mfma_f32_16x16x32_bf16(a1, b1, acc[1][1], 0, 0, 0);
    }

    // P7a: per-column (s2) partial stats in-register; wave covers c = 32w..32w+31
#pragma unroll
    for (int mi = 0; mi < 2; mi++)
#pragma unroll
      for (int r2 = 0; r2 < 4; r2++)
        pb[mi][r2] = post_b[(2 * w + mi) * 16 + quad * 4 + r2];

    float psum0 = 0.f, pss0 = 0.f, psum1 = 0.f, pss1 = 0.f;
#pragma unroll
    for (int mi = 0; mi < 2; mi++)
#pragma unroll
      for (int r2 = 0; r2 < 4; r2++) {
        float v0 = acc[mi][0][r2] + pb[mi][r2];
        float v1 = acc[mi][1][r2] + pb[mi][r2];
        psum0 += v0; pss0 += v0 * v0;
        psum1 += v1; pss1 += v1 * v1;
      }
#pragma unroll
    for (int mm = 16; mm < 64; mm <<= 1) {   // quad tree (l16 / column preserved)
      psum0 += __shfl_xor(psum0, mm);
      pss0  += __shfl_xor(pss0,  mm);
      psum1 += __shfl_xor(psum1, mm);
      pss1  += __shfl_xor(pss1,  mm);
    }
    if (quad == 0) {
      wred[(w * 32 + l16)      * 2 + 0] = psum0;
      wred[(w * 32 + l16)      * 2 + 1] = pss0;
      wred[(w * 32 + 16 + l16) * 2 + 0] = psum1;
      wred[(w * 32 + 16 + l16) * 2 + 1] = pss1;
    }
  }
  __syncthreads();

  // ---- P7b: finalize per-column stats (one wave) ----
  if (tid < 32) {
    float sum = 0.f, ss = 0.f;
#pragma unroll
    for (int w8 = 0; w8 < 8; w8++) {
      sum += wred[(w8 * 32 + tid) * 2 + 0];
      ss  += wred[(w8 * 32 + tid) * 2 + 1];
    }
    float mean = sum * (1.f / 256.f);
    float var  = ss * (1.f / 256.f) - mean * mean;
    statm[tid] = mean;
    statr[tid] = rsqrtf(var + 1e-8f);
  }
  __syncthreads();

  // ---- P8: norm + residual (x reloaded from global, L2-hot) + store, from registers ----
  {
    int s20 = l16, s21 = 16 + l16;
    float m0 = statm[s20], r0 = statr[s20];
    float m1 = statm[s21], r1 = statr[s21];
    bool ok0 = (t0 + s20) < T_;                      // s20 < 16 < TT always
    bool ok1 = (s21 < TT) && ((t0 + s21) < T_);
#pragma unroll
    for (int mi = 0; mi < 2; mi++)
#pragma unroll
      for (int r2 = 0; r2 < 4; r2++) {
        int c = (2 * w + mi) * 16 + quad * 4 + r2;
        float nw = post_nw[c], nb = post_nb[c];
        size_t base = (((size_t)b * C_ + c) * F_ + f) * (size_t)T_;
        if (ok0) {
          size_t idx = base + t0 + s20;
          float v = acc[mi][0][r2] + pb[mi][r2];
          out0[idx] = (v - m0) * r0 * nw + nb + x[idx];
        }
        if (ok1) {
          size_t idx = base + t0 + s21;
          float v = acc[mi][1][r2] + pb[mi][r2];
          out0[idx] = (v - m1) * r1 * nw + nb + x[idx];
        }
      }
  }
}

extern "C" void kernel_launch(void* const* d_in, const int* in_sizes, int n_in,
                              void* d_out, int out_size, void* d_ws, size_t ws_size,
                              hipStream_t stream) {
  const float* x       = (const float*)d_in[0];
  const float* state   = (const float*)d_in[1];
  const float* pre_w   = (const float*)d_in[2];
  const float* pre_b   = (const float*)d_in[3];
  const float* pre_nw  = (const float*)d_in[4];
  const float* pre_nb  = (const float*)d_in[5];
  const float* dw_w    = (const float*)d_in[6];
  const float* dw_b    = (const float*)d_in[7];
  const float* dw_nw   = (const float*)d_in[8];
  const float* dw_nb   = (const float*)d_in[9];
  const float* post_w  = (const float*)d_in[10];
  const float* post_b  = (const float*)d_in[11];
  const float* post_nw = (const float*)d_in[12];
  const float* post_nb = (const float*)d_in[13];

  float* out0 = (float*)d_out;
  float* out1 = out0 + (size_t)B_ * C_ * F_ * T_;

  u16* wpre  = (u16*)d_ws;            // 512KB of ws: bf16 weights (rebuilt every call)
  u16* wpost = wpre + H_ * C_;

  prep_kernel<<<dim3((H_ * C_) / 512), dim3(512), 0, stream>>>(pre_w, post_w, wpre, wpost);
  mixer_kernel<<<dim3(B_ * F_ * NTILE), dim3(512), SMEM_BYTES, stream>>>(
      x, state, pre_b, pre_nw, pre_nb, dw_w, dw_b, dw_nw, dw_nb,
      post_b, post_nw, post_nb, wpre, wpost, out0, out1);
}

// Round 2
// 1053.606 us; speedup vs baseline: 1.4708x; 1.0576x over previous
//
#include <hip/hip_runtime.h>

typedef unsigned short u16;
typedef unsigned int   u32;
typedef __attribute__((ext_vector_type(8))) short s8v;   // 8 bf16 (as shorts) = 4 VGPRs
typedef __attribute__((ext_vector_type(4))) float f4v;   // MFMA C/D frag

constexpr int B_ = 8, C_ = 256, F_ = 64, T_ = 500, H_ = 512;
constexpr int TT = 30;        // output t-columns per block
constexpr int S_ = 32;        // slots = TT + 2 (halo)
constexpr int NTILE = 17;     // ceil(500/30)

constexpr int HROW = 520;     // u16 / hb row (1040B: 16B-aligned, 4-bank skew)
constexpr int XROW = 264;     // u16 / xs row (528B: 16B-aligned)

// LDS map (37,664 B total -> 4 blocks/CU on 160KB = 32 waves = 100% occupancy):
//   hb  [34][520] u16 @ 0     (rows 2..33 alias as h2b[0..31]; rows 32,33 = GEMM2 N-pad)
//   xs  [32][264] u16 @ 0     (ALIASES hb rows 0..16; dead after P1 MFMA loop -> barrier
//                              before GEMM1 writeback overwrites it)
//   wred[8][32][2] f32 @ 35360
//   statm/statr 32 f32 @ 37408 / 37536  (row-stats P2->P4, then col-stats P7b->P8)
constexpr int OFF_HB = 0;
constexpr int OFF_XS = 0;                        // alias!
constexpr int OFF_WR = 34 * HROW * 2;            // 35360
constexpr int OFF_SM = OFF_WR + 2048;            // 37408
constexpr int OFF_SR = OFF_SM + 128;             // 37536
constexpr int SMEM_BYTES = OFF_SR + 128;         // 37664

__device__ __forceinline__ u16 f2bf(float f) {
  unsigned u = __float_as_uint(f);
  u += 0x7FFFu + ((u >> 16) & 1u);        // RNE
  return (u16)(u >> 16);
}
__device__ __forceinline__ float bf2f(u16 h) {
  return __uint_as_float(((unsigned)h) << 16);
}

__global__ void prep_kernel(const float* __restrict__ pw, const float* __restrict__ qw,
                            u16* __restrict__ wa, u16* __restrict__ wb) {
  int i = blockIdx.x * blockDim.x + threadIdx.x;   // 131072 threads exactly
  wa[i] = f2bf(pw[i]);
  wb[i] = f2bf(qw[i]);
}

__global__ __launch_bounds__(512, 8)   // VGPR<=64 so 4 blocks/CU (32 waves) fit
void mixer_kernel(const float* __restrict__ x, const float* __restrict__ state,
                  const float* __restrict__ pre_b, const float* __restrict__ pre_nw,
                  const float* __restrict__ pre_nb,
                  const float* __restrict__ dw_w, const float* __restrict__ dw_b,
                  const float* __restrict__ dw_nw, const float* __restrict__ dw_nb,
                  const float* __restrict__ post_b, const float* __restrict__ post_nw,
                  const float* __restrict__ post_nb,
                  const u16* __restrict__ wpre, const u16* __restrict__ wpost,
                  float* __restrict__ out0, float* __restrict__ out1) {
  extern __shared__ char smem[];
  u16*   hb    = (u16*)  (smem + OFF_HB);   // [34][520]
  u16*   h2b   = hb + 2 * HROW;             // [32][520] = hb rows 2..33
  u16*   xs    = (u16*)  (smem + OFF_XS);   // [32][264] bf16 x tile (aliases hb!)
  float* wred  = (float*)(smem + OFF_WR);   // [8][32][2] per-wave col partials
  float* statm = (float*)(smem + OFF_SM);
  float* statr = (float*)(smem + OFF_SR);

  const int tid  = threadIdx.x;
  const int bx   = blockIdx.x;
  const int tile = bx % NTILE;
  const int f    = (bx / NTILE) % F_;
  const int b    = bx / (NTILE * F_);
  const int t0   = tile * TT;

  const int w    = tid >> 6;        // wave 0..7
  const int lane = tid & 63;
  const int quad = lane >> 4;
  const int l16  = lane & 15;

  // ---- P0: stage x tile as bf16 pairs (slot s -> t = t0-2+s), zero OOB ----
  {
    const float* xp = x + ((size_t)b * C_ * F_ + f) * T_;
    for (int e = tid; e < 128 * S_; e += 512) {     // 4096 c-pairs
      int cpair = e >> 5, s = e & 31;
      int c = cpair * 2;
      int t = t0 - 2 + s;
      float va = 0.f, vb = 0.f;
      if (t >= 0 && t < T_) {
        va = xp[(size_t)c * F_ * T_ + t];
        vb = xp[(size_t)(c + 1) * F_ * T_ + t];
      }
      u32 pk = (u32)f2bf(va) | ((u32)f2bf(vb) << 16);
      *(u32*)(xs + s * XROW + c) = pk;
    }
    // zero hb rows 32,33 == h2b N-pad rows 30,31 (beyond xs alias region: byte 33280+)
    hb[32 * HROW + tid] = 0;
    hb[33 * HROW + tid] = 0;
  }
  __syncthreads();

  // ---- P1: GEMM1  D[s][o] = x^T * pre_w^T ; acc in regs; barrier (xs dies);
  //          then relu(+pre_b) -> hb (bf16), overwriting the xs alias region ----
  {
    f4v acc[2][4];
#pragma unroll
    for (int mi = 0; mi < 2; mi++)
#pragma unroll
      for (int j = 0; j < 4; j++) acc[mi][j] = (f4v){0.f, 0.f, 0.f, 0.f};

    const u16* wp[4];
#pragma unroll
    for (int j = 0; j < 4; j++)
      wp[j] = wpre + ((w + 8 * j) * 16 + l16) * C_ + quad * 8;
    const u16* a0p = xs + l16 * XROW + quad * 8;
    const u16* a1p = xs + (16 + l16) * XROW + quad * 8;

#pragma unroll 2
    for (int k = 0; k < 8; k++) {
      int c0 = k * 32;
      s8v af0 = *(const s8v*)(a0p + c0);
      s8v af1 = *(const s8v*)(a1p + c0);
#pragma unroll
      for (int j = 0; j < 4; j++) {
        s8v bf = *(const s8v*)(wp[j] + c0);
        acc[0][j] = __builtin_amdgcn_mfma_f32_16x16x32_bf16(af0, bf, acc[0][j], 0, 0, 0);
        acc[1][j] = __builtin_amdgcn_mfma_f32_16x16x32_bf16(af1, bf, acc[1][j], 0, 0, 0);
      }
    }
    __syncthreads();   // all xs reads done before hb writeback overwrites alias region
#pragma unroll
    for (int j = 0; j < 4; j++) {
      int o = (w + 8 * j) * 16 + l16;
      float pb = pre_b[o];
#pragma unroll
      for (int mi = 0; mi < 2; mi++)
#pragma unroll
        for (int r2 = 0; r2 < 4; r2++) {
          int s = mi * 16 + quad * 4 + r2;      // D row = m
          float v = fmaxf(acc[mi][j][r2] + pb, 0.f);
          hb[s * HROW + o] = f2bf(v);
        }
    }
  }
  __syncthreads();

  // ---- P2: per-slot stats over 512 ch (STATS ONLY -> statm/statr[32]) ----
  {
    int r = tid >> 4, p = tid & 15;
    const u16* row = hb + r * HROW;
    float sum = 0.f, ss = 0.f;
#pragma unroll
    for (int i = 0; i < 16; i++) {
      int col = ((i + r) & 15) << 5;            // rotation: spread banks across rows
      u32 pk = *(const u32*)(row + 2 * p + col);
      float v0 = bf2f((u16)(pk & 0xffffu)), v1 = bf2f((u16)(pk >> 16));
      sum += v0 + v1; ss += v0 * v0 + v1 * v1;
    }
#pragma unroll
    for (int mm = 1; mm < 16; mm <<= 1) {
      sum += __shfl_xor(sum, mm, 16);
      ss  += __shfl_xor(ss,  mm, 16);
    }
    float mean = sum * (1.f / 512.f);
    float var  = ss * (1.f / 512.f) - mean * mean;
    float rs   = rsqrtf(var + 1e-8f);
    if (p == 0) { statm[r] = mean; statr[r] = rs; }
  }
  __syncthreads();

  // ---- P4: (norm folded in) depthwise K=3 + relu, IN PLACE (h2b = hb+2 rows).
  //          Also folds old P3: out1 emission (raw rows still intact, column-private)
  //          and tile0 halo direct from global state. ----
  {
    int o = tid;
    float nwp = pre_nw[o], nbp = pre_nb[o];
    float w0 = dw_w[o * 3 + 0], w1 = dw_w[o * 3 + 1], w2 = dw_w[o * 3 + 2];
    float db = dw_b[o];

    if (tile == NTILE - 1) {       // emit new_state = normalized h at t=498,499
      int s0 = T_ - t0;            // slot of t=498
      float a0 = statr[s0] * nwp,     b0 = nbp - statm[s0] * a0;
      float a1 = statr[s0 + 1] * nwp, b1 = nbp - statm[s0 + 1] * a1;
      float* op = out1 + (((size_t)b * H_ + o) * F_ + f) * 2;
      op[0] = bf2f(hb[s0 * HROW + o]) * a0 + b0;
      op[1] = bf2f(hb[(s0 + 1) * HROW + o]) * a1 + b1;
    }

    float v0, v1;
    if (tile == 0) {               // halo = raw state (no norm)
      const float* sp = state + (((size_t)b * H_ + o) * F_ + f) * 2;
      v0 = sp[0]; v1 = sp[1];
    } else {
      float a0 = statr[0] * nwp, b0 = nbp - statm[0] * a0;
      float a1 = statr[1] * nwp, b1 = nbp - statm[1] * a1;
      v0 = bf2f(hb[0 * HROW + o]) * a0 + b0;
      v1 = bf2f(hb[1 * HROW + o]) * a1 + b1;
    }
#pragma unroll 6
    for (int s = 2; s < 32; s++) {
      float a = statr[s] * nwp, bb = nbp - statm[s] * a;
      float v2 = bf2f(hb[s * HROW + o]) * a + bb;   // read before aliased write below
      int t = t0 + s - 2;
      float r = fmaxf(w0 * v0 + w1 * v1 + w2 * v2 + db, 0.f);
      h2b[(s - 2) * HROW + o] = (t < T_) ? f2bf(r) : (u16)0;   // == hb[s*HROW+o]
      v0 = v1; v1 = v2;
    }
  }
  __syncthreads();

  // ---- P5: stats+normalize h2b rows 0..29 (u16-pair ops, bank rotation) ----
  {
    int r = tid >> 4, p = tid & 15;
    if (r < TT) {
      u16* row = h2b + r * HROW;
      float sum = 0.f, ss = 0.f;
#pragma unroll
      for (int i = 0; i < 16; i++) {
        int col = ((i + r) & 15) << 5;
        u32 pk = *(const u32*)(row + 2 * p + col);
        float v0 = bf2f((u16)(pk & 0xffffu)), v1 = bf2f((u16)(pk >> 16));
        sum += v0 + v1; ss += v0 * v0 + v1 * v1;
      }
#pragma unroll
      for (int mm = 1; mm < 16; mm <<= 1) {
        sum += __shfl_xor(sum, mm, 16);
        ss  += __shfl_xor(ss,  mm, 16);
      }
      float mean = sum * (1.f / 512.f);
      float var  = ss * (1.f / 512.f) - mean * mean;
      float rs   = rsqrtf(var + 1e-8f);
#pragma unroll
      for (int i = 0; i < 16; i++) {
        int o = 2 * p + (((i + r) & 15) << 5);
        u32 pk = *(const u32*)(row + o);
        float2 nw2 = *(const float2*)(dw_nw + o);
        float2 nb2 = *(const float2*)(dw_nb + o);
        float v0 = (bf2f((u16)(pk & 0xffffu)) - mean) * rs * nw2.x + nb2.x;
        float v1 = (bf2f((u16)(pk >> 16))     - mean) * rs * nw2.y + nb2.y;
        *(u32*)(row + o) = (u32)f2bf(v0) | ((u32)f2bf(v1) << 16);
      }
    }
  }
  __syncthreads();

  // ---- P6: GEMM2  D[c][s2] = post_w * h2 (acc stays in registers) ----
  f4v acc[2][2];
  float pb[2][4];
  {
#pragma unroll
    for (int mi = 0; mi < 2; mi++)
#pragma unroll
      for (int ni = 0; ni < 2; ni++) acc[mi][ni] = (f4v){0.f, 0.f, 0.f, 0.f};

    const u16* ap0 = wpost + ((2 * w + 0) * 16 + l16) * H_ + quad * 8;
    const u16* ap1 = wpost + ((2 * w + 1) * 16 + l16) * H_ + quad * 8;
    const u16* bp0 = h2b + (0 + l16) * HROW + quad * 8;
    const u16* bp1 = h2b + (16 + l16) * HROW + quad * 8;

#pragma unroll 4
    for (int k = 0; k < 16; k++) {
      int ko = k * 32;
      s8v a0 = *(const s8v*)(ap0 + ko);
      s8v a1 = *(const s8v*)(ap1 + ko);
      s8v b0 = *(const s8v*)(bp0 + ko);
      s8v b1 = *(const s8v*)(bp1 + ko);
      acc[0][0] = __builtin_amdgcn_mfma_f32_16x16x32_bf16(a0, b0, acc[0][0], 0, 0, 0);
      acc[0][1] = __builtin_amdgcn_mfma_f32_16x16x32_bf16(a0, b1, acc[0][1], 0, 0, 0);
      acc[1][0] = __builtin_amdgcn_mfma_f32_16x16x32_bf16(a1, b0, acc[1][0], 0, 0, 0);
      acc[1][1] = __builtin_amdgcn_mfma_f32_16x16x32_bf16(a1, b1, acc[1][1], 0, 0, 0);
    }

    // P7a: per-column (s2) partial stats in-register; wave covers c = 32w..32w+31
#pragma unroll
    for (int mi = 0; mi < 2; mi++)
#pragma unroll
      for (int r2 = 0; r2 < 4; r2++)
        pb[mi][r2] = post_b[(2 * w + mi) * 16 + quad * 4 + r2];

    float psum0 = 0.f, pss0 = 0.f, psum1 = 0.f, pss1 = 0.f;
#pragma unroll
    for (int mi = 0; mi < 2; mi++)
#pragma unroll
      for (int r2 = 0; r2 < 4; r2++) {
        float v0 = acc[mi][0][r2] + pb[mi][r2];
        float v1 = acc[mi][1][r2] + pb[mi][r2];
        psum0 += v0; pss0 += v0 * v0;
        psum1 += v1; pss1 += v1 * v1;
      }
#pragma unroll
    for (int mm = 16; mm < 64; mm <<= 1) {   // quad tree (l16 / column preserved)
      psum0 += __shfl_xor(psum0, mm);
      pss0  += __shfl_xor(pss0,  mm);
      psum1 += __shfl_xor(psum1, mm);
      pss1  += __shfl_xor(pss1,  mm);
    }
    if (quad == 0) {
      wred[(w * 32 + l16)      * 2 + 0] = psum0;
      wred[(w * 32 + l16)      * 2 + 1] = pss0;
      wred[(w * 32 + 16 + l16) * 2 + 0] = psum1;
      wred[(w * 32 + 16 + l16) * 2 + 1] = pss1;
    }
  }
  __syncthreads();

  // ---- P7b: finalize per-column stats (one wave) ----
  if (tid < 32) {
    float sum = 0.f, ss = 0.f;
#pragma unroll
    for (int w8 = 0; w8 < 8; w8++) {
      sum += wred[(w8 * 32 + tid) * 2 + 0];
      ss  += wred[(w8 * 32 + tid) * 2 + 1];
    }
    float mean = sum * (1.f / 256.f);
    float var  = ss * (1.f / 256.f) - mean * mean;
    statm[tid] = mean;
    statr[tid] = rsqrtf(var + 1e-8f);
  }
  __syncthreads();

  // ---- P8: norm + residual (x reloaded from global) + store, from registers ----
  {
    int s20 = l16, s21 = 16 + l16;
    float m0 = statm[s20], r0 = statr[s20];
    float m1 = statm[s21], r1 = statr[s21];
    bool ok0 = (t0 + s20) < T_;                      // s20 < 16 < TT always
    bool ok1 = (s21 < TT) && ((t0 + s21) < T_);
#pragma unroll
    for (int mi = 0; mi < 2; mi++)
#pragma unroll
      for (int r2 = 0; r2 < 4; r2++) {
        int c = (2 * w + mi) * 16 + quad * 4 + r2;
        float nw = post_nw[c], nb = post_nb[c];
        size_t base = (((size_t)b * C_ + c) * F_ + f) * (size_t)T_;
        if (ok0) {
          size_t idx = base + t0 + s20;
          float v = acc[mi][0][r2] + pb[mi][r2];
          out0[idx] = (v - m0) * r0 * nw + nb + x[idx];
        }
        if (ok1) {
          size_t idx = base + t0 + s21;
          float v = acc[mi][1][r2] + pb[mi][r2];
          out0[idx] = (v - m1) * r1 * nw + nb + x[idx];
        }
      }
  }
}

extern "C" void kernel_launch(void* const* d_in, const int* in_sizes, int n_in,
                              void* d_out, int out_size, void* d_ws, size_t ws_size,
                              hipStream_t stream) {
  const float* x       = (const float*)d_in[0];
  const float* state   = (const float*)d_in[1];
  const float* pre_w   = (const float*)d_in[2];
  const float* pre_b   = (const float*)d_in[3];
  const float* pre_nw  = (const float*)d_in[4];
  const float* pre_nb  = (const float*)d_in[5];
  const float* dw_w    = (const float*)d_in[6];
  const float* dw_b    = (const float*)d_in[7];
  const float* dw_nw   = (const float*)d_in[8];
  const float* dw_nb   = (const float*)d_in[9];
  const float* post_w  = (const float*)d_in[10];
  const float* post_b  = (const float*)d_in[11];
  const float* post_nw = (const float*)d_in[12];
  const float* post_nb = (const float*)d_in[13];

  float* out0 = (float*)d_out;
  float* out1 = out0 + (size_t)B_ * C_ * F_ * T_;

  u16* wpre  = (u16*)d_ws;            // 512KB of ws: bf16 weights (rebuilt every call)
  u16* wpost = wpre + H_ * C_;

  prep_kernel<<<dim3((H_ * C_) / 512), dim3(512), 0, stream>>>(pre_w, post_w, wpre, wpost);
  mixer_kernel<<<dim3(B_ * F_ * NTILE), dim3(512), SMEM_BYTES, stream>>>(
      x, state, pre_b, pre_nw, pre_nb, dw_w, dw_b, dw_nw, dw_nb,
      post_b, post_nw, post_nb, wpre, wpost, out0, out1);
}